// Round 3
// baseline (489.686 us; speedup 1.0000x reference)
//
#include <hip/hip_runtime.h>
#include <hip/hip_cooperative_groups.h>
#include <math.h>

namespace cg = cooperative_groups;

#define N_NODES  50000
#define N_HEDGES 50000
#define NNZ_     800000
#define IN_CH    512
#define HID_CH   256
#define OUT_CH   64
#define M_PAD    50048   // staging slack rows for global_load_lds (GEMM2 A reads)
#define NBK      391     // buckets of 128 ids: ceil(50000/128)

typedef __attribute__((ext_vector_type(8))) short bf16x8;
typedef __attribute__((ext_vector_type(4))) float f32x4;

__device__ __forceinline__ unsigned short f2bf(float f) {
    union { float f; unsigned u; } v; v.f = f;
    unsigned r = v.u + 0x7FFFu + ((v.u >> 16) & 1u);   // round-to-nearest-even
    return (unsigned short)(r >> 16);
}
__device__ __forceinline__ float bf2f(unsigned short u) {
    union { unsigned u; float f; } v; v.u = (unsigned)u << 16; return v.f;
}

#define GLL16(g, l)                                                            \
    __builtin_amdgcn_global_load_lds(                                          \
        (const __attribute__((address_space(1))) void*)(g),                    \
        (__attribute__((address_space(3))) void*)(l), 16, 0, 0)

#define AST(p, v) __hip_atomic_store((p), (v), __ATOMIC_RELAXED, __HIP_MEMORY_SCOPE_AGENT)
#define ALD(p)    __hip_atomic_load((p), __ATOMIC_RELAXED, __HIP_MEMORY_SCOPE_AGENT)

// =======================================================================
// Cooperative CSR build: replaces {memset, prep, scan391, bin, buildcsr}.
// 256 blocks x 1024 threads (1 block/CU co-resident), 3 grid syncs.
// cnts layout: [0..399]=bcntH  [400..799]=bcntN  [800..1199]=relH  [1200..1599]=relN
// =======================================================================
__global__ __launch_bounds__(1024, 4) void csr_coop_kernel(
    const float* __restrict__ W1, unsigned short* __restrict__ Wp1,
    const float* __restrict__ W2, unsigned short* __restrict__ Wp2,
    const int* __restrict__ ni, const int* __restrict__ hi,
    int* __restrict__ cnts,
    unsigned* __restrict__ recH, unsigned* __restrict__ recN,
    int* __restrict__ offHg, int* __restrict__ colH, float* __restrict__ Binv,
    int* __restrict__ offNg, int* __restrict__ colN, float* __restrict__ Dinv) {
    cg::grid_group grid = cg::this_grid();
    const int t = threadIdx.x;
    const int blk = blockIdx.x;
    const int gtid = blk * 1024 + t;

    __shared__ int offH[NBK + 1], offN[NBK + 1];     // persists phase2 -> phase3
    __shared__ int sA[512], sB[512];
    __shared__ int cH[NBK], cN[NBK], bH[NBK], bN[NBK];
    __shared__ int lc[128], ps[128], cur[128];

    // ---- phase 0: zero global counters (atomic stores: coherent across XCDs) ----
    if (blk == 0) {
        for (int i = t; i < 1600; i += 1024) AST(&cnts[i], 0);
    }
    grid.sync();

    // ---- phase 1: edge histogram + W1/W2 packs ----
    for (int k = t; k < NBK; k += 1024) { cH[k] = 0; cN[k] = 0; }
    __syncthreads();
    if (gtid < NNZ_ / 4) {
        const int4 nv = *(const int4*)(ni + gtid * 4);
        const int4 hv = *(const int4*)(hi + gtid * 4);
        atomicAdd(&cN[nv.x >> 7], 1); atomicAdd(&cN[nv.y >> 7], 1);
        atomicAdd(&cN[nv.z >> 7], 1); atomicAdd(&cN[nv.w >> 7], 1);
        atomicAdd(&cH[hv.x >> 7], 1); atomicAdd(&cH[hv.y >> 7], 1);
        atomicAdd(&cH[hv.z >> 7], 1); atomicAdd(&cH[hv.w >> 7], 1);
    }
    if (gtid < IN_CH * HID_CH) {
        const int kt = gtid / (HID_CH * 32);
        const int r  = gtid % (HID_CH * 32);
        const int n  = r >> 5, kk = r & 31;
        Wp1[gtid] = f2bf(W1[(size_t)(kt * 32 + kk) * HID_CH + n]);
    }
    if (gtid < HID_CH * OUT_CH) {
        const int kt = gtid / (OUT_CH * 32);
        const int r  = gtid % (OUT_CH * 32);
        const int n  = r >> 5, kk = r & 31;
        Wp2[gtid] = f2bf(W2[(size_t)(kt * 32 + kk) * OUT_CH + n]);
    }
    __syncthreads();
    for (int k = t; k < NBK; k += 1024) {
        if (cH[k]) atomicAdd(&cnts[k], cH[k]);
        if (cN[k]) atomicAdd(&cnts[400 + k], cN[k]);
    }
    grid.sync();

    // ---- phase 2a: per-block local scan of global counts -> offH/offN in LDS ----
    {
        int vH = 0, vN = 0;
        if (t < 512) {
            vH = (t < NBK) ? ALD(&cnts[t]) : 0;
            sA[t] = vH;
        } else {
            const int tt = t - 512;
            vN = (tt < NBK) ? ALD(&cnts[400 + tt]) : 0;
            sB[tt] = vN;
        }
        __syncthreads();
        #pragma unroll
        for (int d = 1; d < 512; d <<= 1) {
            int u = 0;
            if (t < 512) { if (t >= d) u = sA[t - d]; }
            else { const int tt = t - 512; if (tt >= d) u = sB[tt - d]; }
            __syncthreads();
            if (t < 512) sA[t] += u; else sB[t - 512] += u;
            __syncthreads();
        }
        if (t < NBK) offH[t] = sA[t] - vH;
        if (t >= 512 && t - 512 < NBK) offN[t - 512] = sB[t - 512] - vN;
        if (t == NBK - 1) offH[NBK] = sA[t];
        if (t - 512 == NBK - 1) offN[NBK] = sB[t - 512];
        __syncthreads();
    }

    // ---- phase 2b: bin records into bucket slices ----
    for (int k = t; k < NBK; k += 1024) { cH[k] = 0; cN[k] = 0; }
    __syncthreads();
    const int i0 = gtid * 4;
    const bool act = (i0 < NNZ_);
    int4 nv4, hv4;
    if (act) {
        nv4 = *(const int4*)(ni + i0);
        hv4 = *(const int4*)(hi + i0);
        atomicAdd(&cN[nv4.x >> 7], 1); atomicAdd(&cN[nv4.y >> 7], 1);
        atomicAdd(&cN[nv4.z >> 7], 1); atomicAdd(&cN[nv4.w >> 7], 1);
        atomicAdd(&cH[hv4.x >> 7], 1); atomicAdd(&cH[hv4.y >> 7], 1);
        atomicAdd(&cH[hv4.z >> 7], 1); atomicAdd(&cH[hv4.w >> 7], 1);
    }
    __syncthreads();
    for (int k = t; k < NBK; k += 1024) {
        bH[k] = cH[k] ? offH[k] + atomicAdd(&cnts[800 + k], cH[k]) : 0;
        bN[k] = cN[k] ? offN[k] + atomicAdd(&cnts[1200 + k], cN[k]) : 0;
    }
    __syncthreads();
    for (int k = t; k < NBK; k += 1024) { cH[k] = bH[k]; cN[k] = bN[k]; }
    __syncthreads();
    if (act) {
        const int nn[4] = {nv4.x, nv4.y, nv4.z, nv4.w};
        const int hh[4] = {hv4.x, hv4.y, hv4.z, hv4.w};
        #pragma unroll
        for (int k = 0; k < 4; ++k) {
            int p = atomicAdd(&cH[hh[k] >> 7], 1);
            AST(&recH[p], ((unsigned)(hh[k] & 127) << 16) | (unsigned)nn[k]);
            p = atomicAdd(&cN[nn[k] >> 7], 1);
            AST(&recN[p], ((unsigned)(nn[k] & 127) << 16) | (unsigned)hh[k]);
        }
    }
    grid.sync();

    // ---- phase 3: per-bucket CSR build (buckets striped over blocks) ----
    for (int vb = blk; vb < 2 * NBK; vb += gridDim.x) {
        const bool isH = vb < NBK;
        const int b = isH ? vb : vb - NBK;
        const int s = isH ? offH[b] : offN[b];
        const int e = isH ? offH[b + 1] : offN[b + 1];
        const unsigned* rec = isH ? recH : recN;
        int* off = isH ? offHg : offNg;
        int* col = isH ? colH : colN;
        float* inv = isH ? Binv : Dinv;
        __syncthreads();                 // protect lc/ps/cur reuse across vb iters
        if (t < 128) lc[t] = 0;
        __syncthreads();
        for (int i = s + t; i < e; i += 1024)
            atomicAdd(&lc[(int)(ALD(&rec[i]) >> 16)], 1);
        __syncthreads();
        if (t < 128) ps[t] = lc[t];
        __syncthreads();
        #pragma unroll
        for (int d = 1; d < 128; d <<= 1) {
            const int v = (t < 128 && t >= d) ? ps[t - d] : 0;
            __syncthreads();
            if (t < 128) ps[t] += v;
            __syncthreads();
        }
        if (t < 128) {
            const int excl = s + ps[t] - lc[t];
            cur[t] = excl;
            const int id = b * 128 + t;
            if (id < N_NODES) {
                off[id] = excl;
                inv[id] = lc[t] > 0 ? 1.f / (float)lc[t] : 0.f;
            }
        }
        if (b == NBK - 1 && t == 0) off[N_NODES] = isH ? offH[NBK] : offN[NBK];
        __syncthreads();
        for (int i = s + t; i < e; i += 1024) {
            const unsigned r = ALD(&rec[i]);
            const int p = atomicAdd(&cur[r >> 16], 1);
            col[p] = (int)(r & 0xFFFFu);
        }
    }
}

// ---- GEMM1 fused: C[M,256] = bf16(X_f32[M,512]) @ Wp1, bf16 out --------------
__global__ void gemm1_fused_kernel(const float* __restrict__ X,
                                   const unsigned short* __restrict__ Wp,
                                   unsigned short* __restrict__ C, int M) {
    constexpr int BM = 64, BN = 256, K = IN_CH, KT = K / 32;
    __shared__ unsigned short As[BM * 32];    // 4 KB
    __shared__ unsigned short Bs[BN * 32];    // 16 KB
    const int tid  = threadIdx.x;
    const int wave = tid >> 6;
    const int lane = tid & 63;
    const int wr = wave >> 1;                 // 2x2 wave grid: wave tile 32x128
    const int wc = wave & 1;
    const int quad = lane >> 4;
    const int l15  = lane & 15;
    const int row0 = blockIdx.x * BM;

    float4 va[2];
    auto loadA = [&](int kt) {
        #pragma unroll
        for (int r = 0; r < 2; ++r) {
            const int idx = r * 256 + tid;
            const int row = idx >> 3;
            const int kc  = (idx & 7) * 4;
            const int gr  = row0 + row;
            float4 v = make_float4(0.f, 0.f, 0.f, 0.f);
            if (gr < M) v = *(const float4*)(X + (size_t)gr * K + kt * 32 + kc);
            va[r] = v;
        }
    };

    f32x4 acc[2][8];
    #pragma unroll
    for (int mt = 0; mt < 2; ++mt)
        #pragma unroll
        for (int nt = 0; nt < 8; ++nt)
            acc[mt][nt] = (f32x4)0.f;

    loadA(0);
    for (int kt = 0; kt < KT; ++kt) {
        __syncthreads();
        #pragma unroll
        for (int r = 0; r < 2; ++r) {
            const int idx = r * 256 + tid;
            const int row = idx >> 3;
            const int kc  = (idx & 7) * 4;
            ushort4 o;
            o.x = f2bf(va[r].x); o.y = f2bf(va[r].y);
            o.z = f2bf(va[r].z); o.w = f2bf(va[r].w);
            *(ushort4*)(As + row * 32 + kc) = o;
        }
        const size_t bk = (size_t)kt * BN * 32;
        #pragma unroll
        for (int r = 0; r < 4; ++r)
            GLL16(Wp + bk + r * 2048 + (size_t)tid * 8, Bs + r * 2048 + tid * 8);
        __syncthreads();
        if (kt + 1 < KT) loadA(kt + 1);       // T14: issue next A loads early

        bf16x8 af[2], bfr[8];
        #pragma unroll
        for (int mt = 0; mt < 2; ++mt)
            af[mt] = *(const bf16x8*)(As + (wr * 32 + mt * 16 + l15) * 32 + quad * 8);
        #pragma unroll
        for (int nt = 0; nt < 8; ++nt)
            bfr[nt] = *(const bf16x8*)(Bs + (wc * 128 + nt * 16 + l15) * 32 + quad * 8);
        #pragma unroll
        for (int mt = 0; mt < 2; ++mt)
            #pragma unroll
            for (int nt = 0; nt < 8; ++nt)
                acc[mt][nt] = __builtin_amdgcn_mfma_f32_16x16x32_bf16(
                    af[mt], bfr[nt], acc[mt][nt], 0, 0, 0);
    }

    #pragma unroll
    for (int mt = 0; mt < 2; ++mt) {
        const int gr0 = row0 + wr * 32 + mt * 16 + quad * 4;
        #pragma unroll
        for (int nt = 0; nt < 8; ++nt) {
            const int gc = wc * 128 + nt * 16 + l15;
            #pragma unroll
            for (int r = 0; r < 4; ++r) {
                const int gr = gr0 + r;
                if (gr < M) C[(size_t)gr * HID_CH + gc] = f2bf(acc[mt][nt][r]);
            }
        }
    }
}

// ---------------- MFMA bf16 GEMM (layer 2): C[M,N] = A[M,K] @ W[K,N] --------------
template <int BN>
__global__ void mfma_gemm_kernel(const unsigned short* __restrict__ A,
                                 const unsigned short* __restrict__ Wp,
                                 unsigned short* __restrict__ C, int M, int N, int K) {
    constexpr int NT = BN / 32;
    __shared__ unsigned short As[128 * 32];
    __shared__ unsigned short Bs[BN * 32];

    const int tid  = threadIdx.x;
    const int wave = tid >> 6;
    const int lane = tid & 63;
    const int wr = wave >> 1;
    const int wc = wave & 1;
    const int quad = lane >> 4;
    const int l15  = lane & 15;
    const int row0 = blockIdx.y * 128;
    const int col0 = blockIdx.x * BN;

    const size_t a_g0   = (size_t)(row0 + wave * 16 + (lane >> 2)) * K + (lane & 3) * 8;
    const int    a_l0   = (wave * 16 + (lane >> 2)) * 32 + (lane & 3) * 8;
    const size_t b_gbase = ((size_t)col0 + wave * 16 + (lane >> 2)) * 32 + (lane & 3) * 8;
    const int    b_l0   = (wave * 16 + (lane >> 2)) * 32 + (lane & 3) * 8;

    f32x4 acc[4][NT];
    #pragma unroll
    for (int mt = 0; mt < 4; ++mt)
        #pragma unroll
        for (int nt = 0; nt < NT; ++nt)
            acc[mt][nt] = (f32x4)0.f;

    const int KT = K / 32;
    for (int kt = 0; kt < KT; ++kt) {
        __syncthreads();
        GLL16(A + a_g0 + (size_t)kt * 32, As + a_l0);
        GLL16(A + a_g0 + (size_t)(kt * 32) + (size_t)64 * K, As + a_l0 + 64 * 32);
        const size_t bk = (size_t)kt * N * 32;
        GLL16(Wp + bk + b_gbase, Bs + b_l0);
        if (BN == 128)
            GLL16(Wp + bk + b_gbase + 64 * 32, Bs + b_l0 + 64 * 32);
        __syncthreads();

        bf16x8 af[4], bf[NT];
        #pragma unroll
        for (int mt = 0; mt < 4; ++mt)
            af[mt] = *(const bf16x8*)(As + (wr * 64 + mt * 16 + l15) * 32 + quad * 8);
        #pragma unroll
        for (int nt = 0; nt < NT; ++nt)
            bf[nt] = *(const bf16x8*)(Bs + (wc * (BN / 2) + nt * 16 + l15) * 32 + quad * 8);
        #pragma unroll
        for (int mt = 0; mt < 4; ++mt)
            #pragma unroll
            for (int nt = 0; nt < NT; ++nt)
                acc[mt][nt] = __builtin_amdgcn_mfma_f32_16x16x32_bf16(
                    af[mt], bf[nt], acc[mt][nt], 0, 0, 0);
    }

    #pragma unroll
    for (int mt = 0; mt < 4; ++mt) {
        const int gr0 = row0 + wr * 64 + mt * 16 + quad * 4;
        #pragma unroll
        for (int nt = 0; nt < NT; ++nt) {
            const int gc = col0 + wc * (BN / 2) + nt * 16 + l15;
            #pragma unroll
            for (int r = 0; r < 4; ++r) {
                int gr = gr0 + r;
                if (gr < M) C[(size_t)gr * N + gc] = f2bf(acc[mt][nt][r]);
            }
        }
    }
}

// ---------------- gather segment-sum, 256 channels, bf16 -----------------------
// 2 groups of 32 lanes; group g walks the segment at stride 2, 16B (8ch) per lane.
template <bool EPI>
__global__ void gather256_kernel(const unsigned short* __restrict__ src,
                                 unsigned short* __restrict__ dst,
                                 const int* __restrict__ off, const int* __restrict__ col,
                                 const float* __restrict__ scale,
                                 const float* __restrict__ bias, int nrows) {
    int row = blockIdx.x * (blockDim.x >> 6) + (threadIdx.x >> 6);
    if (row >= nrows) return;
    const int lane = threadIdx.x & 63;
    const int g = lane >> 5;
    const int l = lane & 31;
    const int s = off[row], e = off[row + 1];
    float a[8];
    #pragma unroll
    for (int k = 0; k < 8; ++k) a[k] = 0.f;
    int j = s + g;
    for (; j + 2 < e; j += 4) {
        const bf16x8 u0 = *(const bf16x8*)(src + ((size_t)col[j]     << 8) + (l << 3));
        const bf16x8 u1 = *(const bf16x8*)(src + ((size_t)col[j + 2] << 8) + (l << 3));
        #pragma unroll
        for (int k = 0; k < 8; ++k)
            a[k] += bf2f((unsigned short)u0[k]) + bf2f((unsigned short)u1[k]);
    }
    if (j < e) {
        const bf16x8 u = *(const bf16x8*)(src + ((size_t)col[j] << 8) + (l << 3));
        #pragma unroll
        for (int k = 0; k < 8; ++k) a[k] += bf2f((unsigned short)u[k]);
    }
    #pragma unroll
    for (int k = 0; k < 8; ++k) a[k] += __shfl_xor(a[k], 32);
    if (g != 0) return;
    const float sc = scale[row];
    float v[8];
    #pragma unroll
    for (int k = 0; k < 8; ++k) v[k] = a[k] * sc;
    if (EPI) {
        const float4 b0 = *(const float4*)(bias + (l << 3));
        const float4 b1 = *(const float4*)(bias + (l << 3) + 4);
        v[0] = fmaxf(v[0] + b0.x, 0.f); v[1] = fmaxf(v[1] + b0.y, 0.f);
        v[2] = fmaxf(v[2] + b0.z, 0.f); v[3] = fmaxf(v[3] + b0.w, 0.f);
        v[4] = fmaxf(v[4] + b1.x, 0.f); v[5] = fmaxf(v[5] + b1.y, 0.f);
        v[6] = fmaxf(v[6] + b1.z, 0.f); v[7] = fmaxf(v[7] + b1.w, 0.f);
    }
    bf16x8 o;
    #pragma unroll
    for (int k = 0; k < 8; ++k) o[k] = (short)f2bf(v[k]);
    *(bf16x8*)(dst + ((size_t)row << 8) + (l << 3)) = o;
}

// ------- gather segment-sum, 64 ch: 8 groups of 8 lanes, 16B (8ch) per lane -------
// group g strides the segment by 8; lane l holds channels 8l..8l+7.
template <bool LSM>
__global__ void gather64_kernel(const unsigned short* __restrict__ src, void* __restrict__ dstv,
                                const int* __restrict__ off, const int* __restrict__ col,
                                const float* __restrict__ scale,
                                const float* __restrict__ bias, int nrows) {
    int row = blockIdx.x * (blockDim.x >> 6) + (threadIdx.x >> 6);
    if (row >= nrows) return;
    const int lane = threadIdx.x & 63;
    const int g = lane >> 3;
    const int l = lane & 7;
    const int s = off[row], e = off[row + 1];
    float a[8];
    #pragma unroll
    for (int k = 0; k < 8; ++k) a[k] = 0.f;
    int j = s + g;
    for (; j + 8 < e; j += 16) {
        const bf16x8 u0 = *(const bf16x8*)(src + ((size_t)col[j]     << 6) + (l << 3));
        const bf16x8 u1 = *(const bf16x8*)(src + ((size_t)col[j + 8] << 6) + (l << 3));
        #pragma unroll
        for (int k = 0; k < 8; ++k)
            a[k] += bf2f((unsigned short)u0[k]) + bf2f((unsigned short)u1[k]);
    }
    if (j < e) {
        const bf16x8 u = *(const bf16x8*)(src + ((size_t)col[j] << 6) + (l << 3));
        #pragma unroll
        for (int k = 0; k < 8; ++k) a[k] += bf2f((unsigned short)u[k]);
    }
    #pragma unroll
    for (int k = 0; k < 8; ++k) {
        a[k] += __shfl_xor(a[k], 8);
        a[k] += __shfl_xor(a[k], 16);
        a[k] += __shfl_xor(a[k], 32);
    }
    const float sc = scale[row];
    float v[8];
    #pragma unroll
    for (int k = 0; k < 8; ++k) v[k] = a[k] * sc;
    if (LSM) {
        const float4 b0 = *(const float4*)(bias + (l << 3));
        const float4 b1 = *(const float4*)(bias + (l << 3) + 4);
        v[0] += b0.x; v[1] += b0.y; v[2] += b0.z; v[3] += b0.w;
        v[4] += b1.x; v[5] += b1.y; v[6] += b1.z; v[7] += b1.w;
        float m = v[0];
        #pragma unroll
        for (int k = 1; k < 8; ++k) m = fmaxf(m, v[k]);
        m = fmaxf(m, __shfl_xor(m, 1));
        m = fmaxf(m, __shfl_xor(m, 2));
        m = fmaxf(m, __shfl_xor(m, 4));
        float su = 0.f;
        #pragma unroll
        for (int k = 0; k < 8; ++k) su += expf(v[k] - m);
        su += __shfl_xor(su, 1);
        su += __shfl_xor(su, 2);
        su += __shfl_xor(su, 4);
        const float lg = m + logf(su);
        if (g == 0) {
            float* dp = (float*)dstv + (size_t)row * OUT_CH + (l << 3);
            float4 o0, o1;
            o0.x = v[0] - lg; o0.y = v[1] - lg; o0.z = v[2] - lg; o0.w = v[3] - lg;
            o1.x = v[4] - lg; o1.y = v[5] - lg; o1.z = v[6] - lg; o1.w = v[7] - lg;
            *(float4*)dp = o0;
            *(float4*)(dp + 4) = o1;
        }
    } else if (g == 0) {
        bf16x8 o;
        #pragma unroll
        for (int k = 0; k < 8; ++k) o[k] = (short)f2bf(v[k]);
        *(bf16x8*)((unsigned short*)dstv + (size_t)row * OUT_CH + (l << 3)) = o;
    }
}

extern "C" void kernel_launch(void* const* d_in, const int* in_sizes, int n_in,
                              void* d_out, int out_size, void* d_ws, size_t ws_size,
                              hipStream_t stream) {
    const float* x  = (const float*)d_in[0];
    const int*   ei = (const int*)d_in[1];
    const float* W1 = (const float*)d_in[2];
    const float* b1 = (const float*)d_in[3];
    const float* W2 = (const float*)d_in[4];
    const float* b2 = (const float*)d_in[5];
    float* out = (float*)d_out;

    const int* node_idx  = ei;
    const int* hedge_idx = ei + NNZ_;

    const size_t RCAP = (size_t)M_PAD * IN_CH / 2;   // floats; 51.25 MB per region
    float* regionA = (float*)d_ws;
    float* regionB = regionA + RCAP;
    float* Dinv = regionB + RCAP;
    float* Binv = Dinv + N_NODES;
    int* offN = (int*)(Binv + N_HEDGES);             // N_NODES+1
    int* offH = offN + N_NODES + 1;                  // N_HEDGES+1
    int* colN = offH + N_HEDGES + 1;                 // NNZ
    int* colH = colN + NNZ_;                         // NNZ
    unsigned short* Wp1 = (unsigned short*)(colH + NNZ_);
    unsigned short* Wp2 = Wp1 + IN_CH * HID_CH;
    int* cnts = (int*)(Wp2 + HID_CH * OUT_CH);       // 1600 ints

    // transient CSR-build records alias regionA (dead until GEMM1 writes h1)
    unsigned* recH = (unsigned*)regionA;             // NNZ
    unsigned* recN = recH + NNZ_;                    // NNZ

    unsigned short* h1_bf = (unsigned short*)regionA;            // 50000 x 256
    unsigned short* m1_bf = (unsigned short*)regionB;            // 50000 x 256
    unsigned short* h2_bf = (unsigned short*)regionA;            // M_PAD x 256 (h1 dead)
    unsigned short* g_bf  = (unsigned short*)regionB;            // 50000 x 64 (m1 dead)
    unsigned short* m2_bf = (unsigned short*)regionB + (size_t)M_PAD * OUT_CH; // 50000 x 64

    // ---- single cooperative dispatch: zero + histogram/W-pack + bin + CSR ----
    {
        const float* a0 = W1; unsigned short* a1 = Wp1;
        const float* a2 = W2; unsigned short* a3 = Wp2;
        const int* a4 = node_idx; const int* a5 = hedge_idx;
        int* a6 = cnts;
        unsigned* a7 = recH; unsigned* a8 = recN;
        int* a9 = offH; int* a10 = colH; float* a11 = Binv;
        int* a12 = offN; int* a13 = colN; float* a14 = Dinv;
        void* args[] = {&a0, &a1, &a2, &a3, &a4, &a5, &a6, &a7,
                        &a8, &a9, &a10, &a11, &a12, &a13, &a14};
        hipLaunchCooperativeKernel((void*)csr_coop_kernel, dim3(256), dim3(1024),
                                   args, 0, stream);
    }

    // ---- layer 1: h1 = bf16(x) @ W1 (fused cvt + MFMA, X read once) ----
    gemm1_fused_kernel<<<(N_NODES + 63) / 64, 256, 0, stream>>>(x, Wp1, h1_bf, N_NODES);
    gather256_kernel<false><<<(N_HEDGES + 3) / 4, 256, 0, stream>>>(
        h1_bf, m1_bf, offH, colH, Binv, nullptr, N_HEDGES);
    gather256_kernel<true><<<(N_NODES + 3) / 4, 256, 0, stream>>>(
        m1_bf, h2_bf, offN, colN, Dinv, b1, N_NODES);

    // ---- layer 2: g = h2 @ W2 (MFMA bf16) ----
    mfma_gemm_kernel<64><<<dim3(OUT_CH / 64, (N_NODES + 127) / 128), 256, 0, stream>>>(
        h2_bf, Wp2, g_bf, N_NODES, OUT_CH, HID_CH);
    gather64_kernel<false><<<(N_HEDGES + 3) / 4, 256, 0, stream>>>(
        g_bf, m2_bf, offH, colH, Binv, nullptr, N_HEDGES);
    gather64_kernel<true><<<(N_NODES + 3) / 4, 256, 0, stream>>>(
        m2_bf, out, offN, colN, Dinv, b2, N_NODES);
}

// Round 6
// 397.608 us; speedup vs baseline: 1.2316x; 1.2316x over previous
//
#include <hip/hip_runtime.h>
#include <math.h>

#define N_NODES  50000
#define N_HEDGES 50000
#define NNZ_     800000
#define IN_CH    512
#define HID_CH   256
#define OUT_CH   64
#define M_PAD    50048   // staging slack rows for global_load_lds (GEMM2 A reads)
#define NBK      391     // buckets of 128 ids: ceil(50000/128)

// prep kernel grid partition (256-thread blocks)
#define BH_BLK   98
#define PK1_BLK  512     // 512*256/256
#define PK2_BLK  64      // 256*64/256

typedef __attribute__((ext_vector_type(8))) short bf16x8;
typedef __attribute__((ext_vector_type(4))) float f32x4;

__device__ __forceinline__ unsigned short f2bf(float f) {
    union { float f; unsigned u; } v; v.f = f;
    unsigned r = v.u + 0x7FFFu + ((v.u >> 16) & 1u);   // round-to-nearest-even
    return (unsigned short)(r >> 16);
}
__device__ __forceinline__ float bf2f(unsigned short u) {
    union { unsigned u; float f; } v; v.u = (unsigned)u << 16; return v.f;
}

#define GLL16(g, l)                                                            \
    __builtin_amdgcn_global_load_lds(                                          \
        (const __attribute__((address_space(1))) void*)(g),                    \
        (__attribute__((address_space(3))) void*)(l), 16, 0, 0)

// ---- prep: fused  bucket histogram | W1 pack | W2 pack  (x-cvt fused in GEMM1) ----
__global__ void prep_kernel(const float* __restrict__ W1, unsigned short* __restrict__ Wp1,
                            const float* __restrict__ W2, unsigned short* __restrict__ Wp2,
                            const int* __restrict__ ni, const int* __restrict__ hi,
                            int* __restrict__ bcntN, int* __restrict__ bcntH) {
    const int blk = blockIdx.x;
    const int t = threadIdx.x;
    if (blk < BH_BLK) {
        __shared__ int lh[NBK], ln[NBK];
        for (int k = t; k < NBK; k += 256) { lh[k] = 0; ln[k] = 0; }
        __syncthreads();
        for (int i4 = blk * 256 + t; i4 < NNZ_ / 4; i4 += BH_BLK * 256) {
            const int4 nv = *(const int4*)(ni + i4 * 4);
            const int4 hv = *(const int4*)(hi + i4 * 4);
            atomicAdd(&ln[nv.x >> 7], 1); atomicAdd(&ln[nv.y >> 7], 1);
            atomicAdd(&ln[nv.z >> 7], 1); atomicAdd(&ln[nv.w >> 7], 1);
            atomicAdd(&lh[hv.x >> 7], 1); atomicAdd(&lh[hv.y >> 7], 1);
            atomicAdd(&lh[hv.z >> 7], 1); atomicAdd(&lh[hv.w >> 7], 1);
        }
        __syncthreads();
        for (int k = t; k < NBK; k += 256) {
            if (ln[k]) atomicAdd(&bcntN[k], ln[k]);
            if (lh[k]) atomicAdd(&bcntH[k], lh[k]);
        }
    } else if (blk < BH_BLK + PK1_BLK) {
        const int i = (blk - BH_BLK) * 256 + t;
        const int kt = i / (HID_CH * 32);
        const int r  = i % (HID_CH * 32);
        const int n  = r >> 5, kk = r & 31;
        Wp1[i] = f2bf(W1[(size_t)(kt * 32 + kk) * HID_CH + n]);
    } else {
        const int i = (blk - (BH_BLK + PK1_BLK)) * 256 + t;
        const int kt = i / (OUT_CH * 32);
        const int r  = i % (OUT_CH * 32);
        const int n  = r >> 5, kk = r & 31;
        Wp2[i] = f2bf(W2[(size_t)(kt * 32 + kk) * OUT_CH + n]);
    }
}

// ---- 391-entry exclusive scan; writes bucket starts + a mutable cursor copy ----
__global__ void scan391_kernel(const int* __restrict__ cA, int* __restrict__ offA,
                               int* __restrict__ curA,
                               const int* __restrict__ cB, int* __restrict__ offB,
                               int* __restrict__ curB) {
    const int* cnt = blockIdx.x ? cB : cA;
    int* off = blockIdx.x ? offB : offA;
    int* cur = blockIdx.x ? curB : curA;
    __shared__ int sbuf[512];
    const int t = threadIdx.x;      // 512 threads
    const int v = (t < NBK) ? cnt[t] : 0;
    sbuf[t] = v;
    __syncthreads();
    #pragma unroll
    for (int d = 1; d < 512; d <<= 1) {
        int u = (t >= d) ? sbuf[t - d] : 0;
        __syncthreads();
        sbuf[t] += u;
        __syncthreads();
    }
    if (t < NBK) { off[t] = sbuf[t] - v; cur[t] = sbuf[t] - v; }
    if (t == NBK - 1) off[NBK] = sbuf[t];
}

// ---- bin: scatter packed records into bucket slices (mutates bcur cursors) ----
__global__ void bin_kernel(const int* __restrict__ ni, const int* __restrict__ hi,
                           int* __restrict__ bcurN, int* __restrict__ bcurH,
                           unsigned* __restrict__ recN, unsigned* __restrict__ recH) {
    __shared__ int cH[NBK], cN[NBK], bH[NBK], bN[NBK];
    for (int t = threadIdx.x; t < NBK; t += blockDim.x) { cH[t] = 0; cN[t] = 0; }
    __syncthreads();
    const int gid = blockIdx.x * blockDim.x + threadIdx.x;
    const int i0 = gid * 4;
    int4 nv, hv;
    const bool act = (i0 < NNZ_);
    if (act) {
        nv = *(const int4*)(ni + i0);
        hv = *(const int4*)(hi + i0);
        atomicAdd(&cN[nv.x >> 7], 1); atomicAdd(&cN[nv.y >> 7], 1);
        atomicAdd(&cN[nv.z >> 7], 1); atomicAdd(&cN[nv.w >> 7], 1);
        atomicAdd(&cH[hv.x >> 7], 1); atomicAdd(&cH[hv.y >> 7], 1);
        atomicAdd(&cH[hv.z >> 7], 1); atomicAdd(&cH[hv.w >> 7], 1);
    }
    __syncthreads();
    for (int t = threadIdx.x; t < NBK; t += blockDim.x) {
        bH[t] = cH[t] ? atomicAdd(&bcurH[t], cH[t]) : 0;
        bN[t] = cN[t] ? atomicAdd(&bcurN[t], cN[t]) : 0;
    }
    __syncthreads();
    for (int t = threadIdx.x; t < NBK; t += blockDim.x) { cH[t] = bH[t]; cN[t] = bN[t]; }
    __syncthreads();
    if (act) {
        int nn[4] = {nv.x, nv.y, nv.z, nv.w};
        int hh[4] = {hv.x, hv.y, hv.z, hv.w};
        #pragma unroll
        for (int k = 0; k < 4; ++k) {
            int p = atomicAdd(&cH[hh[k] >> 7], 1);
            recH[p] = ((unsigned)(hh[k] & 127) << 16) | (unsigned)nn[k];
            p = atomicAdd(&cN[nn[k] >> 7], 1);
            recN[p] = ((unsigned)(nn[k] & 127) << 16) | (unsigned)hh[k];
        }
    }
}

// ---- buildcsr: per bucket — count, 128-prefix-scan, off+inv write, col fill ----
__global__ void buildcsr_kernel(const int* __restrict__ bstartH, const unsigned* __restrict__ recH,
                                int* __restrict__ offH, int* __restrict__ colH,
                                float* __restrict__ Binv,
                                const int* __restrict__ bstartN, const unsigned* __restrict__ recN,
                                int* __restrict__ offN, int* __restrict__ colN,
                                float* __restrict__ Dinv) {
    int b = blockIdx.x;
    const int* bstart; const unsigned* rec; int* off; int* col; float* inv;
    if (b < NBK) { bstart = bstartH; rec = recH; off = offH; col = colH; inv = Binv; }
    else { b -= NBK; bstart = bstartN; rec = recN; off = offN; col = colN; inv = Dinv; }
    const int s = bstart[b], e = bstart[b + 1];
    const int t = threadIdx.x;
    __shared__ int lc[128], ps[128], cur[128];
    if (t < 128) lc[t] = 0;
    __syncthreads();
    for (int i = s + t; i < e; i += 256) atomicAdd(&lc[rec[i] >> 16], 1);
    __syncthreads();
    if (t < 128) ps[t] = lc[t];
    __syncthreads();
    #pragma unroll
    for (int d = 1; d < 128; d <<= 1) {
        int v = (t >= d && t < 128) ? ps[t - d] : 0;
        __syncthreads();
        if (t < 128) ps[t] += v;
        __syncthreads();
    }
    if (t < 128) {
        const int excl = s + ps[t] - lc[t];
        cur[t] = excl;
        const int id = b * 128 + t;
        if (id < N_NODES) {
            off[id] = excl;
            inv[id] = lc[t] > 0 ? 1.f / (float)lc[t] : 0.f;
        }
    }
    if (b == NBK - 1 && t == 255) off[N_NODES] = bstart[NBK];
    __syncthreads();
    for (int i = s + t; i < e; i += 256) {
        const unsigned r = rec[i];
        const int p = atomicAdd(&cur[r >> 16], 1);
        col[p] = (int)(r & 0xFFFFu);
    }
}

// ---- GEMM1 fused: C[M,256] = bf16(X_f32[M,512]) @ Wp1, bf16 out --------------
__global__ void gemm1_fused_kernel(const float* __restrict__ X,
                                   const unsigned short* __restrict__ Wp,
                                   unsigned short* __restrict__ C, int M) {
    constexpr int BM = 64, BN = 256, K = IN_CH, KT = K / 32;
    __shared__ unsigned short As[BM * 32];    // 4 KB
    __shared__ unsigned short Bs[BN * 32];    // 16 KB
    const int tid  = threadIdx.x;
    const int wave = tid >> 6;
    const int lane = tid & 63;
    const int wr = wave >> 1;                 // 2x2 wave grid: wave tile 32x128
    const int wc = wave & 1;
    const int quad = lane >> 4;
    const int l15  = lane & 15;
    const int row0 = blockIdx.x * BM;

    float4 va[2];
    auto loadA = [&](int kt) {
        #pragma unroll
        for (int r = 0; r < 2; ++r) {
            const int idx = r * 256 + tid;
            const int row = idx >> 3;
            const int kc  = (idx & 7) * 4;
            const int gr  = row0 + row;
            float4 v = make_float4(0.f, 0.f, 0.f, 0.f);
            if (gr < M) v = *(const float4*)(X + (size_t)gr * K + kt * 32 + kc);
            va[r] = v;
        }
    };

    f32x4 acc[2][8];
    #pragma unroll
    for (int mt = 0; mt < 2; ++mt)
        #pragma unroll
        for (int nt = 0; nt < 8; ++nt)
            acc[mt][nt] = (f32x4)0.f;

    loadA(0);
    for (int kt = 0; kt < KT; ++kt) {
        __syncthreads();
        #pragma unroll
        for (int r = 0; r < 2; ++r) {
            const int idx = r * 256 + tid;
            const int row = idx >> 3;
            const int kc  = (idx & 7) * 4;
            ushort4 o;
            o.x = f2bf(va[r].x); o.y = f2bf(va[r].y);
            o.z = f2bf(va[r].z); o.w = f2bf(va[r].w);
            *(ushort4*)(As + row * 32 + kc) = o;
        }
        const size_t bk = (size_t)kt * BN * 32;
        #pragma unroll
        for (int r = 0; r < 4; ++r)
            GLL16(Wp + bk + r * 2048 + (size_t)tid * 8, Bs + r * 2048 + tid * 8);
        __syncthreads();
        if (kt + 1 < KT) loadA(kt + 1);       // T14: issue next A loads early

        bf16x8 af[2], bfr[8];
        #pragma unroll
        for (int mt = 0; mt < 2; ++mt)
            af[mt] = *(const bf16x8*)(As + (wr * 32 + mt * 16 + l15) * 32 + quad * 8);
        #pragma unroll
        for (int nt = 0; nt < 8; ++nt)
            bfr[nt] = *(const bf16x8*)(Bs + (wc * 128 + nt * 16 + l15) * 32 + quad * 8);
        #pragma unroll
        for (int mt = 0; mt < 2; ++mt)
            #pragma unroll
            for (int nt = 0; nt < 8; ++nt)
                acc[mt][nt] = __builtin_amdgcn_mfma_f32_16x16x32_bf16(
                    af[mt], bfr[nt], acc[mt][nt], 0, 0, 0);
    }

    #pragma unroll
    for (int mt = 0; mt < 2; ++mt) {
        const int gr0 = row0 + wr * 32 + mt * 16 + quad * 4;
        #pragma unroll
        for (int nt = 0; nt < 8; ++nt) {
            const int gc = wc * 128 + nt * 16 + l15;
            #pragma unroll
            for (int r = 0; r < 4; ++r) {
                const int gr = gr0 + r;
                if (gr < M) C[(size_t)gr * HID_CH + gc] = f2bf(acc[mt][nt][r]);
            }
        }
    }
}

// ---------------- MFMA bf16 GEMM (layer 2): C[M,N] = A[M,K] @ W[K,N] --------------
template <int BN>
__global__ void mfma_gemm_kernel(const unsigned short* __restrict__ A,
                                 const unsigned short* __restrict__ Wp,
                                 unsigned short* __restrict__ C, int M, int N, int K) {
    constexpr int NT = BN / 32;
    __shared__ unsigned short As[128 * 32];
    __shared__ unsigned short Bs[BN * 32];

    const int tid  = threadIdx.x;
    const int wave = tid >> 6;
    const int lane = tid & 63;
    const int wr = wave >> 1;
    const int wc = wave & 1;
    const int quad = lane >> 4;
    const int l15  = lane & 15;
    const int row0 = blockIdx.y * 128;
    const int col0 = blockIdx.x * BN;

    const size_t a_g0   = (size_t)(row0 + wave * 16 + (lane >> 2)) * K + (lane & 3) * 8;
    const int    a_l0   = (wave * 16 + (lane >> 2)) * 32 + (lane & 3) * 8;
    const size_t b_gbase = ((size_t)col0 + wave * 16 + (lane >> 2)) * 32 + (lane & 3) * 8;
    const int    b_l0   = (wave * 16 + (lane >> 2)) * 32 + (lane & 3) * 8;

    f32x4 acc[4][NT];
    #pragma unroll
    for (int mt = 0; mt < 4; ++mt)
        #pragma unroll
        for (int nt = 0; nt < NT; ++nt)
            acc[mt][nt] = (f32x4)0.f;

    const int KT = K / 32;
    for (int kt = 0; kt < KT; ++kt) {
        __syncthreads();
        GLL16(A + a_g0 + (size_t)kt * 32, As + a_l0);
        GLL16(A + a_g0 + (size_t)(kt * 32) + (size_t)64 * K, As + a_l0 + 64 * 32);
        const size_t bk = (size_t)kt * N * 32;
        GLL16(Wp + bk + b_gbase, Bs + b_l0);
        if (BN == 128)
            GLL16(Wp + bk + b_gbase + 64 * 32, Bs + b_l0 + 64 * 32);
        __syncthreads();

        bf16x8 af[4], bf[NT];
        #pragma unroll
        for (int mt = 0; mt < 4; ++mt)
            af[mt] = *(const bf16x8*)(As + (wr * 64 + mt * 16 + l15) * 32 + quad * 8);
        #pragma unroll
        for (int nt = 0; nt < NT; ++nt)
            bf[nt] = *(const bf16x8*)(Bs + (wc * (BN / 2) + nt * 16 + l15) * 32 + quad * 8);
        #pragma unroll
        for (int mt = 0; mt < 4; ++mt)
            #pragma unroll
            for (int nt = 0; nt < NT; ++nt)
                acc[mt][nt] = __builtin_amdgcn_mfma_f32_16x16x32_bf16(
                    af[mt], bf[nt], acc[mt][nt], 0, 0, 0);
    }

    #pragma unroll
    for (int mt = 0; mt < 4; ++mt) {
        const int gr0 = row0 + wr * 64 + mt * 16 + quad * 4;
        #pragma unroll
        for (int nt = 0; nt < NT; ++nt) {
            const int gc = col0 + wc * (BN / 2) + nt * 16 + l15;
            #pragma unroll
            for (int r = 0; r < 4; ++r) {
                int gr = gr0 + r;
                if (gr < M) C[(size_t)gr * N + gc] = f2bf(acc[mt][nt][r]);
            }
        }
    }
}

// ---------------- gather segment-sum, 256 channels, bf16 -----------------------
// 2 groups of 32 lanes; group g walks the segment at stride 2, 16B (8ch) per lane.
// 4-deep unrolled: 8 edges/wave in flight per iteration.
template <bool EPI>
__global__ void gather256_kernel(const unsigned short* __restrict__ src,
                                 unsigned short* __restrict__ dst,
                                 const int* __restrict__ off, const int* __restrict__ col,
                                 const float* __restrict__ scale,
                                 const float* __restrict__ bias, int nrows) {
    int row = blockIdx.x * (blockDim.x >> 6) + (threadIdx.x >> 6);
    if (row >= nrows) return;
    const int lane = threadIdx.x & 63;
    const int g = lane >> 5;
    const int l = lane & 31;
    const int s = off[row], e = off[row + 1];
    float a[8];
    #pragma unroll
    for (int k = 0; k < 8; ++k) a[k] = 0.f;
    int j = s + g;
    for (; j + 6 < e; j += 8) {
        const bf16x8 u0 = *(const bf16x8*)(src + ((size_t)col[j]     << 8) + (l << 3));
        const bf16x8 u1 = *(const bf16x8*)(src + ((size_t)col[j + 2] << 8) + (l << 3));
        const bf16x8 u2 = *(const bf16x8*)(src + ((size_t)col[j + 4] << 8) + (l << 3));
        const bf16x8 u3 = *(const bf16x8*)(src + ((size_t)col[j + 6] << 8) + (l << 3));
        #pragma unroll
        for (int k = 0; k < 8; ++k)
            a[k] += (bf2f((unsigned short)u0[k]) + bf2f((unsigned short)u1[k])) +
                    (bf2f((unsigned short)u2[k]) + bf2f((unsigned short)u3[k]));
    }
    for (; j < e; j += 2) {
        const bf16x8 u = *(const bf16x8*)(src + ((size_t)col[j] << 8) + (l << 3));
        #pragma unroll
        for (int k = 0; k < 8; ++k) a[k] += bf2f((unsigned short)u[k]);
    }
    #pragma unroll
    for (int k = 0; k < 8; ++k) a[k] += __shfl_xor(a[k], 32);
    if (g != 0) return;
    const float sc = scale[row];
    float v[8];
    #pragma unroll
    for (int k = 0; k < 8; ++k) v[k] = a[k] * sc;
    if (EPI) {
        const float4 b0 = *(const float4*)(bias + (l << 3));
        const float4 b1 = *(const float4*)(bias + (l << 3) + 4);
        v[0] = fmaxf(v[0] + b0.x, 0.f); v[1] = fmaxf(v[1] + b0.y, 0.f);
        v[2] = fmaxf(v[2] + b0.z, 0.f); v[3] = fmaxf(v[3] + b0.w, 0.f);
        v[4] = fmaxf(v[4] + b1.x, 0.f); v[5] = fmaxf(v[5] + b1.y, 0.f);
        v[6] = fmaxf(v[6] + b1.z, 0.f); v[7] = fmaxf(v[7] + b1.w, 0.f);
    }
    bf16x8 o;
    #pragma unroll
    for (int k = 0; k < 8; ++k) o[k] = (short)f2bf(v[k]);
    *(bf16x8*)(dst + ((size_t)row << 8) + (l << 3)) = o;
}

// ------- gather segment-sum, 64 ch: 8 groups of 8 lanes, 16B (8ch) per lane -------
template <bool LSM>
__global__ void gather64_kernel(const unsigned short* __restrict__ src, void* __restrict__ dstv,
                                const int* __restrict__ off, const int* __restrict__ col,
                                const float* __restrict__ scale,
                                const float* __restrict__ bias, int nrows) {
    int row = blockIdx.x * (blockDim.x >> 6) + (threadIdx.x >> 6);
    if (row >= nrows) return;
    const int lane = threadIdx.x & 63;
    const int g = lane >> 3;
    const int l = lane & 7;
    const int s = off[row], e = off[row + 1];
    float a[8];
    #pragma unroll
    for (int k = 0; k < 8; ++k) a[k] = 0.f;
    int j = s + g;
    for (; j + 8 < e; j += 16) {
        const bf16x8 u0 = *(const bf16x8*)(src + ((size_t)col[j]     << 6) + (l << 3));
        const bf16x8 u1 = *(const bf16x8*)(src + ((size_t)col[j + 8] << 6) + (l << 3));
        #pragma unroll
        for (int k = 0; k < 8; ++k)
            a[k] += bf2f((unsigned short)u0[k]) + bf2f((unsigned short)u1[k]);
    }
    if (j < e) {
        const bf16x8 u = *(const bf16x8*)(src + ((size_t)col[j] << 6) + (l << 3));
        #pragma unroll
        for (int k = 0; k < 8; ++k) a[k] += bf2f((unsigned short)u[k]);
    }
    #pragma unroll
    for (int k = 0; k < 8; ++k) {
        a[k] += __shfl_xor(a[k], 8);
        a[k] += __shfl_xor(a[k], 16);
        a[k] += __shfl_xor(a[k], 32);
    }
    const float sc = scale[row];
    float v[8];
    #pragma unroll
    for (int k = 0; k < 8; ++k) v[k] = a[k] * sc;
    if (LSM) {
        const float4 b0 = *(const float4*)(bias + (l << 3));
        const float4 b1 = *(const float4*)(bias + (l << 3) + 4);
        v[0] += b0.x; v[1] += b0.y; v[2] += b0.z; v[3] += b0.w;
        v[4] += b1.x; v[5] += b1.y; v[6] += b1.z; v[7] += b1.w;
        float m = v[0];
        #pragma unroll
        for (int k = 1; k < 8; ++k) m = fmaxf(m, v[k]);
        m = fmaxf(m, __shfl_xor(m, 1));
        m = fmaxf(m, __shfl_xor(m, 2));
        m = fmaxf(m, __shfl_xor(m, 4));
        float su = 0.f;
        #pragma unroll
        for (int k = 0; k < 8; ++k) su += expf(v[k] - m);
        su += __shfl_xor(su, 1);
        su += __shfl_xor(su, 2);
        su += __shfl_xor(su, 4);
        const float lg = m + logf(su);
        if (g == 0) {
            float* dp = (float*)dstv + (size_t)row * OUT_CH + (l << 3);
            float4 o0, o1;
            o0.x = v[0] - lg; o0.y = v[1] - lg; o0.z = v[2] - lg; o0.w = v[3] - lg;
            o1.x = v[4] - lg; o1.y = v[5] - lg; o1.z = v[6] - lg; o1.w = v[7] - lg;
            *(float4*)dp = o0;
            *(float4*)(dp + 4) = o1;
        }
    } else if (g == 0) {
        bf16x8 o;
        #pragma unroll
        for (int k = 0; k < 8; ++k) o[k] = (short)f2bf(v[k]);
        *(bf16x8*)((unsigned short*)dstv + (size_t)row * OUT_CH + (l << 3)) = o;
    }
}

extern "C" void kernel_launch(void* const* d_in, const int* in_sizes, int n_in,
                              void* d_out, int out_size, void* d_ws, size_t ws_size,
                              hipStream_t stream) {
    const float* x  = (const float*)d_in[0];
    const int*   ei = (const int*)d_in[1];
    const float* W1 = (const float*)d_in[2];
    const float* b1 = (const float*)d_in[3];
    const float* W2 = (const float*)d_in[4];
    const float* b2 = (const float*)d_in[5];
    float* out = (float*)d_out;

    const int* node_idx  = ei;
    const int* hedge_idx = ei + NNZ_;

    const size_t RCAP = (size_t)M_PAD * IN_CH / 2;   // floats; 51.25 MB per region
    float* regionA = (float*)d_ws;
    float* regionB = regionA + RCAP;
    float* Dinv = regionB + RCAP;
    float* Binv = Dinv + N_NODES;
    int* offN = (int*)(Binv + N_HEDGES);             // N_NODES+1
    int* offH = offN + N_NODES + 1;                  // N_HEDGES+1
    int* colN = offH + N_HEDGES + 1;                 // NNZ
    int* colH = colN + NNZ_;                         // NNZ
    unsigned short* Wp1 = (unsigned short*)(colH + NNZ_);
    unsigned short* Wp2 = Wp1 + IN_CH * HID_CH;
    int* bcntH   = (int*)(Wp2 + HID_CH * OUT_CH);    // 400
    int* bcntN   = bcntH + 400;                      // 400
    int* bstartH = bcntN + 400;                      // 392 used
    int* bstartN = bstartH + 400;
    int* bcurH   = bstartN + 400;
    int* bcurN   = bcurH + 400;

    // transient CSR-build records alias regionA (dead until GEMM1 writes h1)
    unsigned* recH = (unsigned*)regionA;             // NNZ
    unsigned* recN = recH + NNZ_;                    // NNZ

    unsigned short* h1_bf = (unsigned short*)regionA;            // 50000 x 256
    unsigned short* m1_bf = (unsigned short*)regionB;            // 50000 x 256
    unsigned short* h2_bf = (unsigned short*)regionA;            // M_PAD x 256 (h1 dead)
    unsigned short* g_bf  = (unsigned short*)regionB;            // 50000 x 64 (m1 dead)
    unsigned short* m2_bf = (unsigned short*)regionB + (size_t)M_PAD * OUT_CH; // 50000 x 64

    // ---- fused prep + CSR build ----
    hipMemsetAsync(bcntH, 0, 800 * sizeof(int), stream);
    prep_kernel<<<BH_BLK + PK1_BLK + PK2_BLK, 256, 0, stream>>>(
        W1, Wp1, W2, Wp2, node_idx, hedge_idx, bcntN, bcntH);
    scan391_kernel<<<2, 512, 0, stream>>>(bcntH, bstartH, bcurH, bcntN, bstartN, bcurN);
    bin_kernel<<<200, 1024, 0, stream>>>(node_idx, hedge_idx, bcurN, bcurH, recN, recH);
    buildcsr_kernel<<<2 * NBK, 256, 0, stream>>>(bstartH, recH, offH, colH, Binv,
                                                 bstartN, recN, offN, colN, Dinv);

    // ---- layer 1: h1 = bf16(x) @ W1 (fused cvt + MFMA, X read once) ----
    gemm1_fused_kernel<<<(N_NODES + 63) / 64, 256, 0, stream>>>(x, Wp1, h1_bf, N_NODES);
    gather256_kernel<false><<<(N_HEDGES + 3) / 4, 256, 0, stream>>>(
        h1_bf, m1_bf, offH, colH, Binv, nullptr, N_HEDGES);
    gather256_kernel<true><<<(N_NODES + 3) / 4, 256, 0, stream>>>(
        m1_bf, h2_bf, offN, colN, Dinv, b1, N_NODES);

    // ---- layer 2: g = h2 @ W2 (MFMA bf16) ----
    mfma_gemm_kernel<64><<<dim3(OUT_CH / 64, (N_NODES + 127) / 128), 256, 0, stream>>>(
        h2_bf, Wp2, g_bf, N_NODES, OUT_CH, HID_CH);
    gather64_kernel<false><<<(N_HEDGES + 3) / 4, 256, 0, stream>>>(
        g_bf, m2_bf, offH, colH, Binv, nullptr, N_HEDGES);
    gather64_kernel<true><<<(N_NODES + 3) / 4, 256, 0, stream>>>(
        m2_bf, out, offN, colN, Dinv, b2, N_NODES);
}

// Round 7
// 387.205 us; speedup vs baseline: 1.2647x; 1.0269x over previous
//
#include <hip/hip_runtime.h>
#include <math.h>

#define N_NODES  50000
#define N_HEDGES 50000
#define NNZ_     800000
#define IN_CH    512
#define HID_CH   256
#define OUT_CH   64
#define M_PAD    50048   // staging slack rows for global_load_lds (GEMM2 A reads)
#define NBK      391     // buckets of 128 ids: ceil(50000/128)

// prep kernel grid partition (256-thread blocks)
#define BH_BLK   98
#define PKW1_BLK 16      // 16 kt-tiles, LDS-transposed coalesced pack
#define PK2_BLK  64      // 256*64/256

typedef __attribute__((ext_vector_type(8))) short bf16x8;
typedef __attribute__((ext_vector_type(4))) float f32x4;

__device__ __forceinline__ unsigned short f2bf(float f) {
    union { float f; unsigned u; } v; v.f = f;
    unsigned r = v.u + 0x7FFFu + ((v.u >> 16) & 1u);   // round-to-nearest-even
    return (unsigned short)(r >> 16);
}
__device__ __forceinline__ float bf2f(unsigned short u) {
    union { unsigned u; float f; } v; v.u = (unsigned)u << 16; return v.f;
}

#define GLL16(g, l)                                                            \
    __builtin_amdgcn_global_load_lds(                                          \
        (const __attribute__((address_space(1))) void*)(g),                    \
        (__attribute__((address_space(3))) void*)(l), 16, 0, 0)

// ---- prep: fused  bucket histogram | W1 pack (LDS-coalesced) | W2 pack ----
// cnts layout: [0..399]=bcntH  [400..799]=bcntN  [800..1199]=relH  [1200..1599]=relN
__global__ void prep_kernel(const float* __restrict__ W1, unsigned short* __restrict__ Wp1,
                            const float* __restrict__ W2, unsigned short* __restrict__ Wp2,
                            const int* __restrict__ ni, const int* __restrict__ hi,
                            int* __restrict__ cnts) {
    const int blk = blockIdx.x;
    const int t = threadIdx.x;
    __shared__ float smf[256 * 33];          // W1-tile staging; aliased as hist ints
    if (blk < BH_BLK) {
        int* lh = (int*)smf;                 // [NBK]
        int* ln = lh + NBK;                  // [NBK]
        for (int k = t; k < NBK; k += 256) { lh[k] = 0; ln[k] = 0; }
        __syncthreads();
        for (int i4 = blk * 256 + t; i4 < NNZ_ / 4; i4 += BH_BLK * 256) {
            const int4 nv = *(const int4*)(ni + i4 * 4);
            const int4 hv = *(const int4*)(hi + i4 * 4);
            atomicAdd(&ln[nv.x >> 7], 1); atomicAdd(&ln[nv.y >> 7], 1);
            atomicAdd(&ln[nv.z >> 7], 1); atomicAdd(&ln[nv.w >> 7], 1);
            atomicAdd(&lh[hv.x >> 7], 1); atomicAdd(&lh[hv.y >> 7], 1);
            atomicAdd(&lh[hv.z >> 7], 1); atomicAdd(&lh[hv.w >> 7], 1);
        }
        __syncthreads();
        for (int k = t; k < NBK; k += 256) {
            if (lh[k]) atomicAdd(&cnts[k], lh[k]);
            if (ln[k]) atomicAdd(&cnts[400 + k], ln[k]);
        }
    } else if (blk < BH_BLK + PKW1_BLK) {
        // W1 pack, kt-tile: Wp1[kt*8192 + n*32 + kk] = bf16(W1[(kt*32+kk)*256 + n])
        const int kt = blk - BH_BLK;
        #pragma unroll 4
        for (int r = 0; r < 32; ++r)         // coalesced read: 256 consecutive floats
            smf[t * 33 + r] = W1[(size_t)(kt * 32 + r) * HID_CH + t];
        __syncthreads();
        unsigned short* dst = Wp1 + kt * 8192;
        #pragma unroll
        for (int rep = 0; rep < 4; ++rep) {  // coalesced write: consecutive 16B chunks
            const int it = rep * 256 + t;
            const int n = it >> 2, o = it & 3;
            const float* src = &smf[n * 33 + o * 8];
            ushort4 w0, w1;
            w0.x = f2bf(src[0]); w0.y = f2bf(src[1]);
            w0.z = f2bf(src[2]); w0.w = f2bf(src[3]);
            w1.x = f2bf(src[4]); w1.y = f2bf(src[5]);
            w1.z = f2bf(src[6]); w1.w = f2bf(src[7]);
            *(ushort4*)(dst + n * 32 + o * 8) = w0;
            *(ushort4*)(dst + n * 32 + o * 8 + 4) = w1;
        }
    } else {
        const int i = (blk - (BH_BLK + PKW1_BLK)) * 256 + t;
        const int kt = i / (OUT_CH * 32);
        const int r  = i % (OUT_CH * 32);
        const int n  = r >> 5, kk = r & 31;
        Wp2[i] = f2bf(W2[(size_t)(kt * 32 + kk) * OUT_CH + n]);
    }
}

// ---- bin: local scan of global counts (replaces scan391) + record scatter ----
__global__ void bin_kernel(const int* __restrict__ ni, const int* __restrict__ hi,
                           int* __restrict__ cnts,
                           int* __restrict__ bstartH, int* __restrict__ bstartN,
                           unsigned* __restrict__ recN, unsigned* __restrict__ recH) {
    __shared__ int sA[512], sB[512];
    __shared__ int offH[NBK + 1], offN[NBK + 1];
    __shared__ int cH[NBK], cN[NBK], bH[NBK], bN[NBK];
    const int t = threadIdx.x;               // 1024 threads
    int* relH = cnts + 800;
    int* relN = cnts + 1200;

    // local exclusive scan of the two 391-count arrays (H in sA, N in sB)
    int vH = 0, vN = 0;
    if (t < 512) { vH = (t < NBK) ? cnts[t] : 0; sA[t] = vH; }
    else { const int tt = t - 512; vN = (tt < NBK) ? cnts[400 + tt] : 0; sB[tt] = vN; }
    __syncthreads();
    #pragma unroll
    for (int d = 1; d < 512; d <<= 1) {
        int u = 0;
        if (t < 512) { if (t >= d) u = sA[t - d]; }
        else { const int tt = t - 512; if (tt >= d) u = sB[tt - d]; }
        __syncthreads();
        if (t < 512) sA[t] += u; else sB[t - 512] += u;
        __syncthreads();
    }
    if (t < NBK) offH[t] = sA[t] - vH;
    if (t >= 512 && t - 512 < NBK) offN[t - 512] = sB[t - 512] - vN;
    if (t == NBK - 1) offH[NBK] = sA[t];
    if (t - 512 == NBK - 1) offN[NBK] = sB[t - 512];
    __syncthreads();
    if (blockIdx.x == 0) {                   // publish bucket starts for buildcsr
        for (int i = t; i <= NBK; i += 1024) {
            bstartH[i] = offH[i];
            bstartN[i] = offN[i];
        }
    }

    // bin records into bucket slices
    for (int k = t; k < NBK; k += 1024) { cH[k] = 0; cN[k] = 0; }
    __syncthreads();
    const int gid = blockIdx.x * 1024 + t;
    const int i0 = gid * 4;
    int4 nv, hv;
    const bool act = (i0 < NNZ_);
    if (act) {
        nv = *(const int4*)(ni + i0);
        hv = *(const int4*)(hi + i0);
        atomicAdd(&cN[nv.x >> 7], 1); atomicAdd(&cN[nv.y >> 7], 1);
        atomicAdd(&cN[nv.z >> 7], 1); atomicAdd(&cN[nv.w >> 7], 1);
        atomicAdd(&cH[hv.x >> 7], 1); atomicAdd(&cH[hv.y >> 7], 1);
        atomicAdd(&cH[hv.z >> 7], 1); atomicAdd(&cH[hv.w >> 7], 1);
    }
    __syncthreads();
    for (int k = t; k < NBK; k += 1024) {
        bH[k] = cH[k] ? offH[k] + atomicAdd(&relH[k], cH[k]) : 0;
        bN[k] = cN[k] ? offN[k] + atomicAdd(&relN[k], cN[k]) : 0;
    }
    __syncthreads();
    for (int k = t; k < NBK; k += 1024) { cH[k] = bH[k]; cN[k] = bN[k]; }
    __syncthreads();
    if (act) {
        int nn[4] = {nv.x, nv.y, nv.z, nv.w};
        int hh[4] = {hv.x, hv.y, hv.z, hv.w};
        #pragma unroll
        for (int k = 0; k < 4; ++k) {
            int p = atomicAdd(&cH[hh[k] >> 7], 1);
            recH[p] = ((unsigned)(hh[k] & 127) << 16) | (unsigned)nn[k];
            p = atomicAdd(&cN[nn[k] >> 7], 1);
            recN[p] = ((unsigned)(nn[k] & 127) << 16) | (unsigned)hh[k];
        }
    }
}

// ---- buildcsr: per bucket — count, 128-prefix-scan, off+inv write, col fill ----
__global__ void buildcsr_kernel(const int* __restrict__ bstartH, const unsigned* __restrict__ recH,
                                int* __restrict__ offH, int* __restrict__ colH,
                                float* __restrict__ Binv,
                                const int* __restrict__ bstartN, const unsigned* __restrict__ recN,
                                int* __restrict__ offN, int* __restrict__ colN,
                                float* __restrict__ Dinv) {
    int b = blockIdx.x;
    const int* bstart; const unsigned* rec; int* off; int* col; float* inv;
    if (b < NBK) { bstart = bstartH; rec = recH; off = offH; col = colH; inv = Binv; }
    else { b -= NBK; bstart = bstartN; rec = recN; off = offN; col = colN; inv = Dinv; }
    const int s = bstart[b], e = bstart[b + 1];
    const int t = threadIdx.x;
    __shared__ int lc[128], ps[128], cur[128];
    if (t < 128) lc[t] = 0;
    __syncthreads();
    for (int i = s + t; i < e; i += 256) atomicAdd(&lc[rec[i] >> 16], 1);
    __syncthreads();
    if (t < 128) ps[t] = lc[t];
    __syncthreads();
    #pragma unroll
    for (int d = 1; d < 128; d <<= 1) {
        int v = (t >= d && t < 128) ? ps[t - d] : 0;
        __syncthreads();
        if (t < 128) ps[t] += v;
        __syncthreads();
    }
    if (t < 128) {
        const int excl = s + ps[t] - lc[t];
        cur[t] = excl;
        const int id = b * 128 + t;
        if (id < N_NODES) {
            off[id] = excl;
            inv[id] = lc[t] > 0 ? 1.f / (float)lc[t] : 0.f;
        }
    }
    if (b == NBK - 1 && t == 255) off[N_NODES] = bstart[NBK];
    __syncthreads();
    for (int i = s + t; i < e; i += 256) {
        const unsigned r = rec[i];
        const int p = atomicAdd(&cur[r >> 16], 1);
        col[p] = (int)(r & 0xFFFFu);
    }
}

// ---- GEMM1 fused: C[M,256] = bf16(X_f32[M,512]) @ Wp1, bf16 out --------------
__global__ void gemm1_fused_kernel(const float* __restrict__ X,
                                   const unsigned short* __restrict__ Wp,
                                   unsigned short* __restrict__ C, int M) {
    constexpr int BM = 64, BN = 256, K = IN_CH, KT = K / 32;
    __shared__ unsigned short As[BM * 32];    // 4 KB
    __shared__ unsigned short Bs[BN * 32];    // 16 KB
    const int tid  = threadIdx.x;
    const int wave = tid >> 6;
    const int lane = tid & 63;
    const int wr = wave >> 1;                 // 2x2 wave grid: wave tile 32x128
    const int wc = wave & 1;
    const int quad = lane >> 4;
    const int l15  = lane & 15;
    const int row0 = blockIdx.x * BM;

    float4 va[2];
    auto loadA = [&](int kt) {
        #pragma unroll
        for (int r = 0; r < 2; ++r) {
            const int idx = r * 256 + tid;
            const int row = idx >> 3;
            const int kc  = (idx & 7) * 4;
            const int gr  = row0 + row;
            float4 v = make_float4(0.f, 0.f, 0.f, 0.f);
            if (gr < M) v = *(const float4*)(X + (size_t)gr * K + kt * 32 + kc);
            va[r] = v;
        }
    };

    f32x4 acc[2][8];
    #pragma unroll
    for (int mt = 0; mt < 2; ++mt)
        #pragma unroll
        for (int nt = 0; nt < 8; ++nt)
            acc[mt][nt] = (f32x4)0.f;

    loadA(0);
    for (int kt = 0; kt < KT; ++kt) {
        __syncthreads();
        #pragma unroll
        for (int r = 0; r < 2; ++r) {
            const int idx = r * 256 + tid;
            const int row = idx >> 3;
            const int kc  = (idx & 7) * 4;
            ushort4 o;
            o.x = f2bf(va[r].x); o.y = f2bf(va[r].y);
            o.z = f2bf(va[r].z); o.w = f2bf(va[r].w);
            *(ushort4*)(As + row * 32 + kc) = o;
        }
        const size_t bk = (size_t)kt * BN * 32;
        #pragma unroll
        for (int r = 0; r < 4; ++r)
            GLL16(Wp + bk + r * 2048 + (size_t)tid * 8, Bs + r * 2048 + tid * 8);
        __syncthreads();
        if (kt + 1 < KT) loadA(kt + 1);       // T14: issue next A loads early

        bf16x8 af[2], bfr[8];
        #pragma unroll
        for (int mt = 0; mt < 2; ++mt)
            af[mt] = *(const bf16x8*)(As + (wr * 32 + mt * 16 + l15) * 32 + quad * 8);
        #pragma unroll
        for (int nt = 0; nt < 8; ++nt)
            bfr[nt] = *(const bf16x8*)(Bs + (wc * 128 + nt * 16 + l15) * 32 + quad * 8);
        #pragma unroll
        for (int mt = 0; mt < 2; ++mt)
            #pragma unroll
            for (int nt = 0; nt < 8; ++nt)
                acc[mt][nt] = __builtin_amdgcn_mfma_f32_16x16x32_bf16(
                    af[mt], bfr[nt], acc[mt][nt], 0, 0, 0);
    }

    #pragma unroll
    for (int mt = 0; mt < 2; ++mt) {
        const int gr0 = row0 + wr * 32 + mt * 16 + quad * 4;
        #pragma unroll
        for (int nt = 0; nt < 8; ++nt) {
            const int gc = wc * 128 + nt * 16 + l15;
            #pragma unroll
            for (int r = 0; r < 4; ++r) {
                const int gr = gr0 + r;
                if (gr < M) C[(size_t)gr * HID_CH + gc] = f2bf(acc[mt][nt][r]);
            }
        }
    }
}

// ---------------- MFMA bf16 GEMM (layer 2): C[M,N] = A[M,K] @ W[K,N] --------------
template <int BN>
__global__ void mfma_gemm_kernel(const unsigned short* __restrict__ A,
                                 const unsigned short* __restrict__ Wp,
                                 unsigned short* __restrict__ C, int M, int N, int K) {
    constexpr int NT = BN / 32;
    __shared__ unsigned short As[128 * 32];
    __shared__ unsigned short Bs[BN * 32];

    const int tid  = threadIdx.x;
    const int wave = tid >> 6;
    const int lane = tid & 63;
    const int wr = wave >> 1;
    const int wc = wave & 1;
    const int quad = lane >> 4;
    const int l15  = lane & 15;
    const int row0 = blockIdx.y * 128;
    const int col0 = blockIdx.x * BN;

    const size_t a_g0   = (size_t)(row0 + wave * 16 + (lane >> 2)) * K + (lane & 3) * 8;
    const int    a_l0   = (wave * 16 + (lane >> 2)) * 32 + (lane & 3) * 8;
    const size_t b_gbase = ((size_t)col0 + wave * 16 + (lane >> 2)) * 32 + (lane & 3) * 8;
    const int    b_l0   = (wave * 16 + (lane >> 2)) * 32 + (lane & 3) * 8;

    f32x4 acc[4][NT];
    #pragma unroll
    for (int mt = 0; mt < 4; ++mt)
        #pragma unroll
        for (int nt = 0; nt < NT; ++nt)
            acc[mt][nt] = (f32x4)0.f;

    const int KT = K / 32;
    for (int kt = 0; kt < KT; ++kt) {
        __syncthreads();
        GLL16(A + a_g0 + (size_t)kt * 32, As + a_l0);
        GLL16(A + a_g0 + (size_t)(kt * 32) + (size_t)64 * K, As + a_l0 + 64 * 32);
        const size_t bk = (size_t)kt * N * 32;
        GLL16(Wp + bk + b_gbase, Bs + b_l0);
        if (BN == 128)
            GLL16(Wp + bk + b_gbase + 64 * 32, Bs + b_l0 + 64 * 32);
        __syncthreads();

        bf16x8 af[4], bf[NT];
        #pragma unroll
        for (int mt = 0; mt < 4; ++mt)
            af[mt] = *(const bf16x8*)(As + (wr * 64 + mt * 16 + l15) * 32 + quad * 8);
        #pragma unroll
        for (int nt = 0; nt < NT; ++nt)
            bf[nt] = *(const bf16x8*)(Bs + (wc * (BN / 2) + nt * 16 + l15) * 32 + quad * 8);
        #pragma unroll
        for (int mt = 0; mt < 4; ++mt)
            #pragma unroll
            for (int nt = 0; nt < NT; ++nt)
                acc[mt][nt] = __builtin_amdgcn_mfma_f32_16x16x32_bf16(
                    af[mt], bf[nt], acc[mt][nt], 0, 0, 0);
    }

    #pragma unroll
    for (int mt = 0; mt < 4; ++mt) {
        const int gr0 = row0 + wr * 64 + mt * 16 + quad * 4;
        #pragma unroll
        for (int nt = 0; nt < NT; ++nt) {
            const int gc = col0 + wc * (BN / 2) + nt * 16 + l15;
            #pragma unroll
            for (int r = 0; r < 4; ++r) {
                int gr = gr0 + r;
                if (gr < M) C[(size_t)gr * N + gc] = f2bf(acc[mt][nt][r]);
            }
        }
    }
}

// ---------------- gather segment-sum, 256 channels, bf16 -----------------------
// 2 groups of 32 lanes; group g walks the segment at stride 2, 16B (8ch) per lane.
// 4-deep unrolled: 8 edges/wave in flight per iteration.
template <bool EPI>
__global__ void gather256_kernel(const unsigned short* __restrict__ src,
                                 unsigned short* __restrict__ dst,
                                 const int* __restrict__ off, const int* __restrict__ col,
                                 const float* __restrict__ scale,
                                 const float* __restrict__ bias, int nrows) {
    int row = blockIdx.x * (blockDim.x >> 6) + (threadIdx.x >> 6);
    if (row >= nrows) return;
    const int lane = threadIdx.x & 63;
    const int g = lane >> 5;
    const int l = lane & 31;
    const int s = off[row], e = off[row + 1];
    float a[8];
    #pragma unroll
    for (int k = 0; k < 8; ++k) a[k] = 0.f;
    int j = s + g;
    for (; j + 6 < e; j += 8) {
        const bf16x8 u0 = *(const bf16x8*)(src + ((size_t)col[j]     << 8) + (l << 3));
        const bf16x8 u1 = *(const bf16x8*)(src + ((size_t)col[j + 2] << 8) + (l << 3));
        const bf16x8 u2 = *(const bf16x8*)(src + ((size_t)col[j + 4] << 8) + (l << 3));
        const bf16x8 u3 = *(const bf16x8*)(src + ((size_t)col[j + 6] << 8) + (l << 3));
        #pragma unroll
        for (int k = 0; k < 8; ++k)
            a[k] += (bf2f((unsigned short)u0[k]) + bf2f((unsigned short)u1[k])) +
                    (bf2f((unsigned short)u2[k]) + bf2f((unsigned short)u3[k]));
    }
    for (; j < e; j += 2) {
        const bf16x8 u = *(const bf16x8*)(src + ((size_t)col[j] << 8) + (l << 3));
        #pragma unroll
        for (int k = 0; k < 8; ++k) a[k] += bf2f((unsigned short)u[k]);
    }
    #pragma unroll
    for (int k = 0; k < 8; ++k) a[k] += __shfl_xor(a[k], 32);
    if (g != 0) return;
    const float sc = scale[row];
    float v[8];
    #pragma unroll
    for (int k = 0; k < 8; ++k) v[k] = a[k] * sc;
    if (EPI) {
        const float4 b0 = *(const float4*)(bias + (l << 3));
        const float4 b1 = *(const float4*)(bias + (l << 3) + 4);
        v[0] = fmaxf(v[0] + b0.x, 0.f); v[1] = fmaxf(v[1] + b0.y, 0.f);
        v[2] = fmaxf(v[2] + b0.z, 0.f); v[3] = fmaxf(v[3] + b0.w, 0.f);
        v[4] = fmaxf(v[4] + b1.x, 0.f); v[5] = fmaxf(v[5] + b1.y, 0.f);
        v[6] = fmaxf(v[6] + b1.z, 0.f); v[7] = fmaxf(v[7] + b1.w, 0.f);
    }
    bf16x8 o;
    #pragma unroll
    for (int k = 0; k < 8; ++k) o[k] = (short)f2bf(v[k]);
    *(bf16x8*)(dst + ((size_t)row << 8) + (l << 3)) = o;
}

// ------- gather segment-sum, 64 ch: 8 groups of 8 lanes, 16B (8ch) per lane -------
template <bool LSM>
__global__ void gather64_kernel(const unsigned short* __restrict__ src, void* __restrict__ dstv,
                                const int* __restrict__ off, const int* __restrict__ col,
                                const float* __restrict__ scale,
                                const float* __restrict__ bias, int nrows) {
    int row = blockIdx.x * (blockDim.x >> 6) + (threadIdx.x >> 6);
    if (row >= nrows) return;
    const int lane = threadIdx.x & 63;
    const int g = lane >> 3;
    const int l = lane & 7;
    const int s = off[row], e = off[row + 1];
    float a[8];
    #pragma unroll
    for (int k = 0; k < 8; ++k) a[k] = 0.f;
    int j = s + g;
    for (; j + 8 < e; j += 16) {
        const bf16x8 u0 = *(const bf16x8*)(src + ((size_t)col[j]     << 6) + (l << 3));
        const bf16x8 u1 = *(const bf16x8*)(src + ((size_t)col[j + 8] << 6) + (l << 3));
        #pragma unroll
        for (int k = 0; k < 8; ++k)
            a[k] += bf2f((unsigned short)u0[k]) + bf2f((unsigned short)u1[k]);
    }
    if (j < e) {
        const bf16x8 u = *(const bf16x8*)(src + ((size_t)col[j] << 6) + (l << 3));
        #pragma unroll
        for (int k = 0; k < 8; ++k) a[k] += bf2f((unsigned short)u[k]);
    }
    #pragma unroll
    for (int k = 0; k < 8; ++k) {
        a[k] += __shfl_xor(a[k], 8);
        a[k] += __shfl_xor(a[k], 16);
        a[k] += __shfl_xor(a[k], 32);
    }
    const float sc = scale[row];
    float v[8];
    #pragma unroll
    for (int k = 0; k < 8; ++k) v[k] = a[k] * sc;
    if (LSM) {
        const float4 b0 = *(const float4*)(bias + (l << 3));
        const float4 b1 = *(const float4*)(bias + (l << 3) + 4);
        v[0] += b0.x; v[1] += b0.y; v[2] += b0.z; v[3] += b0.w;
        v[4] += b1.x; v[5] += b1.y; v[6] += b1.z; v[7] += b1.w;
        float m = v[0];
        #pragma unroll
        for (int k = 1; k < 8; ++k) m = fmaxf(m, v[k]);
        m = fmaxf(m, __shfl_xor(m, 1));
        m = fmaxf(m, __shfl_xor(m, 2));
        m = fmaxf(m, __shfl_xor(m, 4));
        float su = 0.f;
        #pragma unroll
        for (int k = 0; k < 8; ++k) su += expf(v[k] - m);
        su += __shfl_xor(su, 1);
        su += __shfl_xor(su, 2);
        su += __shfl_xor(su, 4);
        const float lg = m + logf(su);
        if (g == 0) {
            float* dp = (float*)dstv + (size_t)row * OUT_CH + (l << 3);
            float4 o0, o1;
            o0.x = v[0] - lg; o0.y = v[1] - lg; o0.z = v[2] - lg; o0.w = v[3] - lg;
            o1.x = v[4] - lg; o1.y = v[5] - lg; o1.z = v[6] - lg; o1.w = v[7] - lg;
            *(float4*)dp = o0;
            *(float4*)(dp + 4) = o1;
        }
    } else if (g == 0) {
        bf16x8 o;
        #pragma unroll
        for (int k = 0; k < 8; ++k) o[k] = (short)f2bf(v[k]);
        *(bf16x8*)((unsigned short*)dstv + (size_t)row * OUT_CH + (l << 3)) = o;
    }
}

extern "C" void kernel_launch(void* const* d_in, const int* in_sizes, int n_in,
                              void* d_out, int out_size, void* d_ws, size_t ws_size,
                              hipStream_t stream) {
    const float* x  = (const float*)d_in[0];
    const int*   ei = (const int*)d_in[1];
    const float* W1 = (const float*)d_in[2];
    const float* b1 = (const float*)d_in[3];
    const float* W2 = (const float*)d_in[4];
    const float* b2 = (const float*)d_in[5];
    float* out = (float*)d_out;

    const int* node_idx  = ei;
    const int* hedge_idx = ei + NNZ_;

    const size_t RCAP = (size_t)M_PAD * IN_CH / 2;   // floats; 51.25 MB per region
    float* regionA = (float*)d_ws;
    float* regionB = regionA + RCAP;
    float* Dinv = regionB + RCAP;
    float* Binv = Dinv + N_NODES;
    int* offN = (int*)(Binv + N_HEDGES);             // N_NODES+1
    int* offH = offN + N_NODES + 1;                  // N_HEDGES+1
    int* colN = offH + N_HEDGES + 1;                 // NNZ
    int* colH = colN + NNZ_;                         // NNZ
    unsigned short* Wp1 = (unsigned short*)(colH + NNZ_);
    unsigned short* Wp2 = Wp1 + IN_CH * HID_CH;
    int* cnts    = (int*)(Wp2 + HID_CH * OUT_CH);    // 1600 ints
    int* bstartH = cnts + 1600;                      // 392 used
    int* bstartN = bstartH + 400;

    // transient CSR-build records alias regionA (dead until GEMM1 writes h1)
    unsigned* recH = (unsigned*)regionA;             // NNZ
    unsigned* recN = recH + NNZ_;                    // NNZ

    unsigned short* h1_bf = (unsigned short*)regionA;            // 50000 x 256
    unsigned short* m1_bf = (unsigned short*)regionB;            // 50000 x 256
    unsigned short* h2_bf = (unsigned short*)regionA;            // M_PAD x 256 (h1 dead)
    unsigned short* g_bf  = (unsigned short*)regionB;            // 50000 x 64 (m1 dead)
    unsigned short* m2_bf = (unsigned short*)regionB + (size_t)M_PAD * OUT_CH; // 50000 x 64

    // ---- CSR build chain: memset -> prep -> bin(+scan) -> buildcsr ----
    hipMemsetAsync(cnts, 0, 1600 * sizeof(int), stream);
    prep_kernel<<<BH_BLK + PKW1_BLK + PK2_BLK, 256, 0, stream>>>(
        W1, Wp1, W2, Wp2, node_idx, hedge_idx, cnts);
    bin_kernel<<<200, 1024, 0, stream>>>(node_idx, hedge_idx, cnts,
                                         bstartH, bstartN, recN, recH);
    buildcsr_kernel<<<2 * NBK, 256, 0, stream>>>(bstartH, recH, offH, colH, Binv,
                                                 bstartN, recN, offN, colN, Dinv);

    // ---- layer 1: h1 = bf16(x) @ W1 (fused cvt + MFMA, X read once) ----
    gemm1_fused_kernel<<<(N_NODES + 63) / 64, 256, 0, stream>>>(x, Wp1, h1_bf, N_NODES);
    gather256_kernel<false><<<(N_HEDGES + 3) / 4, 256, 0, stream>>>(
        h1_bf, m1_bf, offH, colH, Binv, nullptr, N_HEDGES);
    gather256_kernel<true><<<(N_NODES + 3) / 4, 256, 0, stream>>>(
        m1_bf, h2_bf, offN, colN, Dinv, b1, N_NODES);

    // ---- layer 2: g = h2 @ W2 (MFMA bf16) ----
    mfma_gemm_kernel<64><<<dim3(OUT_CH / 64, (N_NODES + 127) / 128), 256, 0, stream>>>(
        h2_bf, Wp2, g_bf, N_NODES, OUT_CH, HID_CH);
    gather64_kernel<false><<<(N_HEDGES + 3) / 4, 256, 0, stream>>>(
        g_bf, m2_bf, offH, colH, Binv, nullptr, N_HEDGES);
    gather64_kernel<true><<<(N_NODES + 3) / 4, 256, 0, stream>>>(
        m2_bf, out, offN, colN, Dinv, b2, N_NODES);
}